// Round 8
// baseline (175.669 us; speedup 1.0000x reference)
//
#include <hip/hip_runtime.h>
#include <math.h>

// NoisyTopkRouter, all-f32.
// x[ntok,384] @ {w_route,w_noise}[8,384]^T -> 16 logits/token,
// noisy = logit + noise*softplus(noise_logit), top-2 of 8, sparse softmax.
// Output: [ntok*8 probs f32 | ntok*2 indices-as-f32].
//
// R8: six structural variants all landed ~55-60 us with every pipe <25%.
// Common factor: global x-loads scatter 64 lanes over 8-16 token-rows
// (64-256 B segments, 1536 B apart) -> measured ~1.7 TB/s effective.
// Fix: stage x through LDS with fully-contiguous wave loads (lane i reads
// base + i*16B -> 1 KB/instr), compute from LDS (scatter free there).
// 16-token tile: 24 KB x + 24.8 KB w (padded, route/noise interleaved) ->
// 3 blocks/CU resident; staging of next block overlaps compute of previous.

constexpr int D = 384;
constexpr int TPB = 16;        // tokens per block
constexpr int WS = 388;        // w row stride (dwords): 16B-aligned, breaks p-pair bank collision

__device__ __forceinline__ float dpp_xor1(float v) {   // lane ^ 1, quad_perm [1,0,3,2]
    return __int_as_float(__builtin_amdgcn_update_dpp(
        0, __float_as_int(v), 0xB1, 0xF, 0xF, true));
}
__device__ __forceinline__ float dpp_xor2(float v) {   // lane ^ 2, quad_perm [2,3,0,1]
    return __int_as_float(__builtin_amdgcn_update_dpp(
        0, __float_as_int(v), 0x4E, 0xF, 0xF, true));
}
__device__ __forceinline__ float swz_xor4(float v) {   // ds_swizzle xor 4
    return __int_as_float(__builtin_amdgcn_ds_swizzle(__float_as_int(v), 0x101F));
}
__device__ __forceinline__ float swz_xor8(float v) {   // ds_swizzle xor 8
    return __int_as_float(__builtin_amdgcn_ds_swizzle(__float_as_int(v), 0x201F));
}
__device__ __forceinline__ float swz_xor16(float v) {  // ds_swizzle xor 16
    return __int_as_float(__builtin_amdgcn_ds_swizzle(__float_as_int(v), 0x401F));
}

__global__ __launch_bounds__(256, 3) void noisy_topk_router_f32(
    const float* __restrict__ x,        // [ntok,384]
    const float* __restrict__ noise,    // [ntok,8]
    const float* __restrict__ w_route,  // [8,384]
    const float* __restrict__ b_route,  // [8]
    const float* __restrict__ w_noise,  // [8,384]
    const float* __restrict__ b_noise,  // [8]
    float* __restrict__ out,            // [ntok*8 | ntok*2]
    int ntok)
{
    __shared__ float x_tile[TPB * D];   // 24 KB, packed row-major (staged contiguously)
    __shared__ float w_lds[16 * WS];    // 24.8 KB, row = expert*2 + (0:route,1:noise)
    __shared__ float bias[16];

    const int tid  = threadIdx.x;
    const int tok0 = blockIdx.x * TPB;

    // ---- stage x: 6144 dwords, each wave-instr reads 1 KB fully contiguous ----
    const float* xg = x + (size_t)tok0 * D;
#pragma unroll
    for (int i = 0; i < 6; ++i) {
        const int f = (tid + i * 256) * 4;              // < 6144
        *(float4*)(x_tile + f) = *(const float4*)(xg + f);
    }
    // ---- stage w: contiguous reads, interleaved rows (route=2e, noise=2e+1) ----
#pragma unroll
    for (int i = 0; i < 3; ++i) {
        const int f = (tid + i * 256) * 4;              // < 3072
        const int e = f / 384, d = f - e * 384;
        *(float4*)(w_lds + (2 * e)     * WS + d) = *(const float4*)(w_route + f);
        *(float4*)(w_lds + (2 * e + 1) * WS + d) = *(const float4*)(w_noise + f);
    }
    if (tid < 8)       bias[tid] = b_route[tid];
    else if (tid < 16) bias[tid] = b_noise[tid - 8];
    __syncthreads();

    // thread = (p: route/noise half, c: d-slice 0..15, g: token-pair 0..7)
    const int p = tid & 1;
    const int c = (tid >> 1) & 15;
    const int g = tid >> 5;

    float acc[2][8];
#pragma unroll
    for (int t = 0; t < 2; ++t)
#pragma unroll
        for (int e = 0; e < 8; ++e) acc[t][e] = 0.f;

    const float* xt0 = x_tile + (g * 2) * D;
    const float* xt1 = x_tile + (g * 2 + 1) * D;
    const float* wb  = w_lds + p * WS;

#pragma unroll
    for (int j = 0; j < 6; ++j) {
        const int dof = j * 64 + c * 4;
        float4 x0 = *(const float4*)(xt0 + dof);
        float4 x1 = *(const float4*)(xt1 + dof);
#pragma unroll
        for (int e = 0; e < 8; ++e) {
            float4 wv = *(const float4*)(wb + e * 2 * WS + dof);
            acc[0][e] += x0.x * wv.x + x0.y * wv.y + x0.z * wv.z + x0.w * wv.w;
            acc[1][e] += x1.x * wv.x + x1.y * wv.y + x1.z * wv.z + x1.w * wv.w;
        }
    }

    // reduce over the 16 d-slices (lane bits 1..4):
    // xor2 partitioned (keep token bit = c&1, DPP), then xor4/8/16 plain.
    const bool b0 = (c & 1);
    float a1[8];
#pragma unroll
    for (int e = 0; e < 8; ++e) {
        float s = b0 ? acc[0][e] : acc[1][e];   // send the token we don't keep
        float k = b0 ? acc[1][e] : acc[0][e];   // keep token (c&1)
        a1[e] = k + dpp_xor2(s);
    }
#pragma unroll
    for (int e = 0; e < 8; ++e) a1[e] += swz_xor4(a1[e]);
#pragma unroll
    for (int e = 0; e < 8; ++e) a1[e] += swz_xor8(a1[e]);
#pragma unroll
    for (int e = 0; e < 8; ++e) a1[e] += swz_xor16(a1[e]);

    // pair-exchange: even lanes hold route sums, odd lanes hold noise sums
    float oth[8];
#pragma unroll
    for (int e = 0; e < 8; ++e) oth[e] = dpp_xor1(a1[e]);

    if (p == 0 && c < 2) {
        const int token = tok0 + g * 2 + c;     // 4 writer lanes per wave
        float4 n0 = *(const float4*)(noise + (size_t)token * 8);
        float4 n1 = *(const float4*)(noise + (size_t)token * 8 + 4);
        float nz[8] = {n0.x, n0.y, n0.z, n0.w, n1.x, n1.y, n1.z, n1.w};

        float noisy[8];
#pragma unroll
        for (int e = 0; e < 8; ++e) {
            float lg = a1[e]  + bias[e];        // route logit
            float nl = oth[e] + bias[8 + e];    // noise logit
            // stable softplus: max(z,0) + log1p(exp(-|z|))
            float sp = fmaxf(nl, 0.f) + log1pf(expf(-fabsf(nl)));
            noisy[e] = lg + nz[e] * sp;
        }

        // top-2, jax.lax.top_k tie-break: earliest index wins ties
        float v0 = noisy[0]; int i0 = 0;
#pragma unroll
        for (int e = 1; e < 8; ++e)
            if (noisy[e] > v0) { v0 = noisy[e]; i0 = e; }
        float v1 = -INFINITY; int i1 = 0;
#pragma unroll
        for (int e = 0; e < 8; ++e)
            if (e != i0 && noisy[e] > v1) { v1 = noisy[e]; i1 = e; }

        // 2-way softmax (other experts exactly 0)
        float ex  = expf(v1 - v0);       // v1 <= v0
        float inv = 1.f / (1.f + ex);
        float p0  = inv;
        float p1  = ex * inv;

        float pr[8];
#pragma unroll
        for (int e = 0; e < 8; ++e)
            pr[e] = (e == i0) ? p0 : ((e == i1) ? p1 : 0.f);

        float* orow = out + (size_t)token * 8;
        *(float4*)(orow)     = make_float4(pr[0], pr[1], pr[2], pr[3]);
        *(float4*)(orow + 4) = make_float4(pr[4], pr[5], pr[6], pr[7]);

        *(float2*)(out + (size_t)ntok * 8 + (size_t)token * 2) =
            make_float2((float)i0, (float)i1);
    }
}

extern "C" void kernel_launch(void* const* d_in, const int* in_sizes, int n_in,
                              void* d_out, int out_size, void* d_ws, size_t ws_size,
                              hipStream_t stream) {
    const float* x       = (const float*)d_in[0];
    const float* noise   = (const float*)d_in[1];
    const float* w_route = (const float*)d_in[2];
    const float* b_route = (const float*)d_in[3];
    const float* w_noise = (const float*)d_in[4];
    const float* b_noise = (const float*)d_in[5];
    float* out = (float*)d_out;

    const int ntok   = in_sizes[0] / D;   // 65536
    const int blocks = ntok / TPB;        // 4096 blocks of 16 tokens

    hipLaunchKernelGGL(noisy_topk_router_f32, dim3(blocks), dim3(256), 0, stream,
                       x, noise, w_route, b_route, w_noise, b_noise, out, ntok);
}